// Round 3
// baseline (1604.670 us; speedup 1.0000x reference)
//
#include <hip/hip_runtime.h>

// ---------------------------------------------------------------------------
// Masker: 3-layer MLP trunk (fp16 MFMA, BN in epilogue kernels) +
// 1024-step gumbel-softmax scan.
//
// Key facts exploited:
//  * bias before BatchNorm is mathematically a no-op (mean-subtracted).
//  * exp((m+g)/tau) with tau=0.5, g=-ln(t), t=-ln(u)  ==>  exp(2m)/t^2.
//    -> no row-max needed, only a sum reduction (overflow-safe in fp32).
//  * threefry noise is independent of the scan dynamics -> precompute all
//    noise with a fully parallel kernel; the sequential kernel is then
//    latency-bound on one block-sum per step.
//  * JAX random_bits semantics: modern JAX defaults jax_threefry_partitionable
//    =True -> PER-ELEMENT hash: bits[i] = COMBINE(threefry2x32(key, hi(i)=0,
//    lo(i)=i)) with COMBINE = o0^o1. (Round-2 bug: implemented the legacy
//    split-iota pairing o0(j, j+65536) -> fully decorrelated stream, absmax
//    0.998 invariant to quantization changes.) fold_in is NOT flag-gated:
//    keys[s] = threefry2x32((0,42), (0,s)) unchanged.
//  * fp16 noise storage: t in [1.19e-7, 87.3] underflows fp16 normals ->
//    store t_s = 512*t (exact scaling; range all fp16-normal; the 512^2
//    factor cancels in softmax normalization).
// ---------------------------------------------------------------------------

typedef _Float16 half8 __attribute__((ext_vector_type(8)));
typedef float floatx4 __attribute__((ext_vector_type(4)));

#define TINYF 1.17549435e-38f
#define LN2F  0.69314718055994531f
#define C2F   2.8853900817779268f   // 2*log2(e):  exp(2m) = exp2(m*C2F)
#define TSCALE 512.0f               // noise pre-scale (cancels in softmax)
#define TS_MIN 6.11e-5f             // just above fp16 min normal 6.1035e-5

// partitionable random_bits output combine; flip to (o0) if stream mismatches
#define COMBINE(o0, o1) ((o0) ^ (o1))

#if __has_builtin(__builtin_amdgcn_exp2f)
#define EXP2F(x) __builtin_amdgcn_exp2f(x)
#else
#define EXP2F(x) exp2f(x)
#endif
#if __has_builtin(__builtin_amdgcn_logf)
#define LOG2F(x) __builtin_amdgcn_logf(x)
#else
#define LOG2F(x) __log2f(x)
#endif
#if __has_builtin(__builtin_amdgcn_rcpf)
#define RCPF(x) __builtin_amdgcn_rcpf(x)
#else
#define RCPF(x) (1.0f/(x))
#endif

// ---------------- threefry2x32 (20 rounds), bit-exact vs JAX ----------------
__device__ __forceinline__ unsigned rotl32(unsigned x, int r) {
  return (x << r) | (x >> (32 - r));
}

__device__ __forceinline__ void tf2x32(unsigned k0, unsigned k1,
                                       unsigned x0, unsigned x1,
                                       unsigned &o0, unsigned &o1) {
  unsigned kx = k0 ^ k1 ^ 0x1BD11BDAu;
#define TFR(r) { x0 += x1; x1 = rotl32(x1, (r)); x1 ^= x0; }
  x0 += k0; x1 += k1;
  TFR(13) TFR(15) TFR(26) TFR(6)
  x0 += k1; x1 += kx + 1u;
  TFR(17) TFR(29) TFR(16) TFR(24)
  x0 += kx; x1 += k0 + 2u;
  TFR(13) TFR(15) TFR(26) TFR(6)
  x0 += k0; x1 += k1 + 3u;
  TFR(17) TFR(29) TFR(16) TFR(24)
  x0 += k1; x1 += kx + 4u;
  TFR(13) TFR(15) TFR(26) TFR(6)
  x0 += kx; x1 += k0 + 5u;
#undef TFR
  o0 = x0; o1 = x1;
}

// bits -> u (JAX uniform[tiny,1)) -> t = -ln(u).
// Clamp t >= 1e-7 (< exact min 1.19e-7): guards v_log_f32 absolute error
// near u~1 from producing t <= 0 (-> inf/NaN poisoning).
__device__ __forceinline__ float bits_to_t(unsigned bits) {
  float f = __uint_as_float((bits >> 9) | 0x3f800000u) - 1.0f;
  float u = fmaxf(TINYF, f + TINYF);   // (1-tiny) rounds to 1.0f in fp32
  return fmaxf(-LN2F * LOG2F(u), 1.0e-7f);
}

// keys[s] = fold_in(key(42), s) = threefry2x32((0,42), (0,s))
// (fold_in uses threefry_2x32 on a 2-element count: x0=[0], x1=[s] -> (o0,o1))
__global__ void keys_kernel(unsigned* __restrict__ keys) {
  int i = threadIdx.x;                 // 1024 threads, 1 block
  unsigned o0, o1;
  tf2x32(0u, 42u, 0u, (unsigned)i, o0, o1);
  keys[2*i] = o0; keys[2*i+1] = o1;
}

// f (fp32) -> fp16, 131072 elements
__global__ void cast_kernel(const float* __restrict__ f, _Float16* __restrict__ o) {
  int i = blockIdx.x * 256 + threadIdx.x;
  o[i] = (_Float16)f[i];
}

// ---------------- GEMM: P[kc][64][N] partial = A(64xK fp16) @ W(KxN fp32) ---
// block: 256 thr (4 waves); tile 64 x 128; K-step 32; mfma_f32_16x16x32_f16.
// A-frag: A[m=lane&15][k=(lane>>4)*8+j]; B-frag: B[k=(lane>>4)*8+j][n=lane&15]
// C/D:    D[m=(lane>>4)*4+reg][n=lane&15]   (m89-verified)
__global__ __launch_bounds__(256) void gemm_kernel(
    const _Float16* __restrict__ A, const float* __restrict__ W,
    float* __restrict__ P, int K, int N, int KC) {
  __shared__ _Float16 As[64 * 40];    // pitch 40 halves = 80B (16B-aligned rows)
  __shared__ _Float16 Ws[128 * 40];   // [n][k] layout so B-frags are ds_read_b128
  const int t = threadIdx.x;
  const int lane = t & 63, w = t >> 6;
  const int c0 = blockIdx.x * 128;
  const int k0beg = blockIdx.y * KC, k0end = k0beg + KC;

  floatx4 acc[4][2];
#pragma unroll
  for (int i = 0; i < 4; ++i)
#pragma unroll
    for (int j = 0; j < 2; ++j) acc[i][j] = (floatx4){0.f, 0.f, 0.f, 0.f};

  const int ar = t >> 2;              // A stage: row 0..63
  const int ako = (t & 3) * 8;        // k offset 0,8,16,24
  const int wn = (t & 31) * 4;        // W stage: col 0..124
  const int wk = (t >> 5) * 2;        // k-pair 0..14

  // software pipeline: preload iteration 0
  uint4 av = *(const uint4*)(A + (size_t)ar * K + k0beg + ako);
  float4 wv[2][2];
#pragma unroll
  for (int kk = 0; kk < 2; ++kk) {
    int krow = k0beg + kk * 16 + wk;
    wv[kk][0] = *(const float4*)(W + (size_t)krow * N + c0 + wn);
    wv[kk][1] = *(const float4*)(W + (size_t)(krow + 1) * N + c0 + wn);
  }

  for (int k0 = k0beg; k0 < k0end; k0 += 32) {
    __syncthreads();                  // previous iter's LDS reads done
    *(uint4*)(&As[ar * 40 + ako]) = av;
#pragma unroll
    for (int kk = 0; kk < 2; ++kk) {
#pragma unroll
      for (int i = 0; i < 4; ++i) {
        const float* p0 = (const float*)&wv[kk][0];
        const float* p1 = (const float*)&wv[kk][1];
        _Float16 h0 = (_Float16)p0[i], h1 = (_Float16)p1[i];
        unsigned u = (unsigned)*(unsigned short*)&h0 |
                     ((unsigned)*(unsigned short*)&h1 << 16);
        *(unsigned*)(&Ws[(wn + i) * 40 + kk * 16 + wk]) = u;
      }
    }
    // prefetch next iteration's globals (overlaps MFMA below)
    int kn = k0 + 32;
    if (kn < k0end) {
      av = *(const uint4*)(A + (size_t)ar * K + kn + ako);
#pragma unroll
      for (int kk = 0; kk < 2; ++kk) {
        int krow = kn + kk * 16 + wk;
        wv[kk][0] = *(const float4*)(W + (size_t)krow * N + c0 + wn);
        wv[kk][1] = *(const float4*)(W + (size_t)(krow + 1) * N + c0 + wn);
      }
    }
    __syncthreads();                  // LDS writes visible
    const int q = lane >> 4, ml = lane & 15;
    half8 bfrag[2];
#pragma unroll
    for (int nt = 0; nt < 2; ++nt)
      bfrag[nt] = *(const half8*)(&Ws[(w * 32 + nt * 16 + ml) * 40 + q * 8]);
#pragma unroll
    for (int mt = 0; mt < 4; ++mt) {
      half8 afrag = *(const half8*)(&As[(mt * 16 + ml) * 40 + q * 8]);
      acc[mt][0] = __builtin_amdgcn_mfma_f32_16x16x32_f16(afrag, bfrag[0], acc[mt][0], 0, 0, 0);
      acc[mt][1] = __builtin_amdgcn_mfma_f32_16x16x32_f16(afrag, bfrag[1], acc[mt][1], 0, 0, 0);
    }
  }
  const int q = lane >> 4, ml = lane & 15;
  float* Pb = P + (size_t)blockIdx.y * 64 * N;
#pragma unroll
  for (int mt = 0; mt < 4; ++mt)
#pragma unroll
    for (int nt = 0; nt < 2; ++nt)
#pragma unroll
      for (int i = 0; i < 4; ++i) {
        int m = mt * 16 + q * 4 + i;
        int n = c0 + w * 32 + nt * 16 + ml;
        Pb[(size_t)m * N + n] = acc[mt][nt][i];
      }
}

// ---------------- BN epilogue: sum partials, batch-stats over 64 rows -------
// mode 0: y = relu(xn*g + be) -> fp16 H.  mode 1: y = xn -> fp32 (mask0).
__global__ __launch_bounds__(256) void bn_kernel(
    const float* __restrict__ P, int nkc, int N,
    const float* __restrict__ g, const float* __restrict__ be,
    _Float16* __restrict__ Hout, float* __restrict__ Fout, int mode) {
  int c = blockIdx.x * 256 + threadIdx.x;
  float x[64];
#pragma unroll
  for (int r = 0; r < 64; ++r) x[r] = 0.f;
  for (int kc = 0; kc < nkc; ++kc) {
    const float* Pb = P + (size_t)kc * 64 * N + c;
#pragma unroll
    for (int r = 0; r < 64; ++r) x[r] += Pb[(size_t)r * N];
  }
  float s = 0.f;
#pragma unroll
  for (int r = 0; r < 64; ++r) s += x[r];
  float mean = s * 0.015625f;
  float v = 0.f;
#pragma unroll
  for (int r = 0; r < 64; ++r) { float d = x[r] - mean; v += d * d; }
  v *= 0.015625f;
  float rs = rsqrtf(v + 1e-5f);
  if (mode == 0) {
    float gg = g[c], bb = be[c];
#pragma unroll
    for (int r = 0; r < 64; ++r) {
      float y = (x[r] - mean) * rs * gg + bb;
      Hout[(size_t)r * N + c] = (_Float16)fmaxf(y, 0.f);
    }
  } else {
#pragma unroll
    for (int r = 0; r < 64; ++r)
      Fout[(size_t)r * N + c] = (x[r] - mean) * rs;
  }
}

// ---------------- noise precompute: t_s=512*(-ln u) fp16 --------------------
// Partitionable scheme: element (row r, step s, dim c) has linear index
// i = r*2048+c (< 2^32 -> hi word 0); bits = COMBINE(tf2x32(keys[s], 0, i)).
// layout noise[r*2097152 + sg*8192 + t*32 + q*4 + j]; block = (row r = bx&63,
// stepgroup sg = bx>>6); 256 thr, dims c = 8t..8t+7, steps s = 4sg..4sg+3.
__global__ __launch_bounds__(256) void noise_kernel(
    const unsigned* __restrict__ keys, _Float16* __restrict__ noise) {
  const int bx = blockIdx.x;
  const int r = bx & 63, sg = bx >> 6;
  const int t = threadIdx.x;
  union Pack { unsigned v[16]; unsigned short us[32]; } pa;
#pragma unroll
  for (int j = 0; j < 4; ++j) {
    unsigned kk0 = keys[(sg * 4 + j) * 2];
    unsigned kk1 = keys[(sg * 4 + j) * 2 + 1];
#pragma unroll
    for (int q = 0; q < 8; ++q) {
      unsigned x1 = (unsigned)(r * 2048 + t * 8 + q);
      unsigned o0, o1;
      tf2x32(kk0, kk1, 0u, x1, o0, o1);
      float ts = fmaxf(bits_to_t(COMBINE(o0, o1)) * TSCALE, TS_MIN);
      _Float16 h = (_Float16)ts;
      pa.us[q * 4 + j] = *(unsigned short*)&h;
    }
  }
  size_t base = (((size_t)r * 256 + sg) * 2048 + (size_t)t * 8) * 4;
  uint4* wp = (uint4*)(noise + base);
#pragma unroll
  for (int i = 0; i < 4; ++i) wp[i] = ((uint4*)pa.v)[i];
}

// ---------------- sequential gumbel-softmax scan ----------------------------
// 64 blocks (1 row each) x 256 thr, 8 elems/thread. One sum-reduction/step.
// MODE 0: load precomputed fp16 t_s (prefetched 1 group ahead); the 512^2
//         factor in p cancels in the softmax normalization.
// MODE 1: inline per-element threefry, all-fp32 (ws too small for noise buf).
template <int MODE>
__global__ __launch_bounds__(256) void loop_kernel(
    const float* __restrict__ mask0, const _Float16* __restrict__ noise,
    const unsigned* __restrict__ keys, float* __restrict__ zout) {
  const int row = blockIdx.x;
  const int t = threadIdx.x;
  const int lane = t & 63, w = t >> 6;
  __shared__ __align__(16) float partial[2][4];
  __shared__ unsigned keysLds[2048];
  if (MODE == 1) {
    for (int i = t; i < 2048; i += 256) keysLds[i] = keys[i];
    __syncthreads();
  }
  float m[8], z[8];
  {
    union { float4 v[2]; float f[8]; } mm;
    mm.v[0] = *(const float4*)(mask0 + row * 2048 + t * 8);
    mm.v[1] = *(const float4*)(mask0 + row * 2048 + t * 8 + 4);
#pragma unroll
    for (int q = 0; q < 8; ++q) { m[q] = mm.f[q]; z[q] = 0.f; }
  }
  const _Float16* nbase = nullptr;
  uint4 nbuf[4];
  if (MODE == 0) {
    nbase = noise + (size_t)row * 2097152;   // 256 sg * 8192 halves
    const uint4* p0 = (const uint4*)(nbase + (size_t)t * 32);
    nbuf[0] = p0[0]; nbuf[1] = p0[1]; nbuf[2] = p0[2]; nbuf[3] = p0[3];
  }
  const unsigned idx0 = (unsigned)(row * 2048 + t * 8);  // linear index base

  for (int sg = 0; sg < 256; ++sg) {
    float rg[8][4];                          // rcp(t_s^2), m-independent
    if (MODE == 0) {
      union { uint4 v[4]; unsigned short us[32]; } ub;
      ub.v[0] = nbuf[0]; ub.v[1] = nbuf[1]; ub.v[2] = nbuf[2]; ub.v[3] = nbuf[3];
#pragma unroll
      for (int q = 0; q < 8; ++q)
#pragma unroll
        for (int j = 0; j < 4; ++j) {
          unsigned short h = ub.us[q * 4 + j];
          float tt = (float)*(const _Float16*)&h;
          rg[q][j] = RCPF(tt * tt);
        }
      if (sg + 1 < 256) {                    // prefetch next group (4 steps)
        const uint4* pn = (const uint4*)(nbase + (size_t)(sg + 1) * 8192 + (size_t)t * 32);
        nbuf[0] = pn[0]; nbuf[1] = pn[1]; nbuf[2] = pn[2]; nbuf[3] = pn[3];
      }
    } else {
#pragma unroll
      for (int j = 0; j < 4; ++j) {
        unsigned kk0 = keysLds[(sg * 4 + j) * 2];
        unsigned kk1 = keysLds[(sg * 4 + j) * 2 + 1];
#pragma unroll
        for (int q = 0; q < 8; ++q) {
          unsigned o0, o1;
          tf2x32(kk0, kk1, 0u, idx0 + q, o0, o1);
          float tt = bits_to_t(COMBINE(o0, o1));
          rg[q][j] = RCPF(tt * tt);
        }
      }
    }
#pragma unroll
    for (int j = 0; j < 4; ++j) {
      float p[8], loc = 0.f;
#pragma unroll
      for (int q = 0; q < 8; ++q) {
        p[q] = EXP2F(m[q] * C2F) * rg[q][j]; // exp(2m)/t^2  (x const, cancels)
        loc += p[q];
      }
#pragma unroll
      for (int off = 32; off >= 1; off >>= 1) loc += __shfl_xor(loc, off, 64);
      if (lane == 0) partial[j & 1][w] = loc;
      __syncthreads();                       // slot rotation makes 1 barrier safe
      float4 ps = *(const float4*)(&partial[j & 1][0]);
      float S = (ps.x + ps.y) + (ps.z + ps.w);
      float inv = RCPF(S);
#pragma unroll
      for (int q = 0; q < 8; ++q) {
        m[q] = p[q] * inv;
        z[q] = fmaxf(z[q], m[q]);
      }
    }
  }
  union { float4 v[2]; float f[8]; } oo;
#pragma unroll
  for (int q = 0; q < 8; ++q) oo.f[q] = z[q];
  *(float4*)(zout + row * 2048 + t * 8) = oo.v[0];
  *(float4*)(zout + row * 2048 + t * 8 + 4) = oo.v[1];
}

// ---------------- launcher --------------------------------------------------
#define OFF_A0  65536u
#define OFF_H1  327680u
#define OFF_H2  1376256u
#define OFF_M0  2424832u
#define OFF_P   2949120u
#define OFF_NOISE 33554432ull
#define NEED_PRE (33554432ull + 268435456ull)

extern "C" void kernel_launch(void* const* d_in, const int* in_sizes, int n_in,
                              void* d_out, int out_size, void* d_ws, size_t ws_size,
                              hipStream_t stream) {
  const float* f   = (const float*)d_in[0];
  const float* W1  = (const float*)d_in[1];
  // d_in[2] = b1 (zero; bias is a no-op before BN anyway)
  const float* g1  = (const float*)d_in[3];
  const float* be1 = (const float*)d_in[4];
  const float* W2  = (const float*)d_in[5];
  const float* g2  = (const float*)d_in[7];
  const float* be2 = (const float*)d_in[8];
  const float* W3  = (const float*)d_in[9];

  char* ws = (char*)d_ws;
  unsigned*  keys  = (unsigned*)(ws);
  _Float16*  A0    = (_Float16*)(ws + OFF_A0);
  _Float16*  H1    = (_Float16*)(ws + OFF_H1);
  _Float16*  H2    = (_Float16*)(ws + OFF_H2);
  float*     M0    = (float*)(ws + OFF_M0);
  float*     P     = (float*)(ws + OFF_P);
  _Float16*  noise = (_Float16*)(ws + OFF_NOISE);
  float*     z     = (float*)d_out;
  bool pre = ws_size >= NEED_PRE;

  keys_kernel<<<1, 1024, 0, stream>>>(keys);
  cast_kernel<<<512, 256, 0, stream>>>(f, A0);
  gemm_kernel<<<dim3(64, 8), 256, 0, stream>>>(A0, W1, P, 2048, 8192, 256);
  bn_kernel<<<32, 256, 0, stream>>>(P, 8, 8192, g1, be1, H1, nullptr, 0);
  gemm_kernel<<<dim3(64, 8), 256, 0, stream>>>(H1, W2, P, 8192, 8192, 1024);
  bn_kernel<<<32, 256, 0, stream>>>(P, 8, 8192, g2, be2, H2, nullptr, 0);
  gemm_kernel<<<dim3(16, 32), 256, 0, stream>>>(H2, W3, P, 8192, 2048, 256);
  bn_kernel<<<8, 256, 0, stream>>>(P, 32, 2048, nullptr, nullptr, nullptr, M0, 1);
  if (pre) {
    noise_kernel<<<16384, 256, 0, stream>>>(keys, noise);
    loop_kernel<0><<<64, 256, 0, stream>>>(M0, noise, keys, z);
  } else {
    loop_kernel<1><<<64, 256, 0, stream>>>(M0, nullptr, keys, z);
  }
}

// Round 4
// 1113.620 us; speedup vs baseline: 1.4409x; 1.4409x over previous
//
#include <hip/hip_runtime.h>

// ---------------------------------------------------------------------------
// Masker: 3-layer MLP trunk (fp16 MFMA, BN in epilogue kernels) +
// 1024-step gumbel-softmax scan.
//
//  * JAX partitionable threefry verified R3 (absmax 3.9e-3): bits[i] =
//    o0^o1 of threefry2x32(key, (0, i)); keys[s] = threefry2x32((0,42),(0,s)).
//  * Scan algebra: state kept in UNNORMALIZED p-space. Per step:
//      pn[e] = exp2( p[e]*aC + lg[e] ),  lg = -2*log2(t_s),  aC = C2F/S_prev
//    (tau=0.5 -> exp((m+g)/tau) = e^{2m}/t^2; 512-scale & normalization fold
//    into lg / aC; softmax needs only the sum S -> no row max).
//  * R3 profile: loop_kernel 1130 cyc/step, all-idle (VALU 9.5%, HBM 3.5%)
//    -> serial-latency bound on shfl(ds_bpermute) chain + barrier + 2 muls.
//    This version: DPP wave reduce (~70cyc), lg precomputed per 4-step group
//    (pipelined 2 groups ahead; prep scheduled into the LDS-read shadow).
// ---------------------------------------------------------------------------

typedef _Float16 half8 __attribute__((ext_vector_type(8)));
typedef float floatx4 __attribute__((ext_vector_type(4)));

#define TINYF 1.17549435e-38f
#define LN2F  0.69314718055994531f
#define C2F   2.8853900817779268f   // 2*log2(e)
#define TSCALE 512.0f               // noise pre-scale (cancels in softmax)
#define TS_MIN 6.11e-5f             // just above fp16 min normal

#define COMBINE(o0, o1) ((o0) ^ (o1))

#if __has_builtin(__builtin_amdgcn_exp2f)
#define EXP2F(x) __builtin_amdgcn_exp2f(x)
#else
#define EXP2F(x) exp2f(x)
#endif
#if __has_builtin(__builtin_amdgcn_logf)
#define LOG2F(x) __builtin_amdgcn_logf(x)
#else
#define LOG2F(x) __log2f(x)
#endif
#if __has_builtin(__builtin_amdgcn_rcpf)
#define RCPF(x) __builtin_amdgcn_rcpf(x)
#else
#define RCPF(x) (1.0f/(x))
#endif

// ---------------- threefry2x32 (20 rounds), bit-exact vs JAX ----------------
__device__ __forceinline__ unsigned rotl32(unsigned x, int r) {
  return (x << r) | (x >> (32 - r));
}

__device__ __forceinline__ void tf2x32(unsigned k0, unsigned k1,
                                       unsigned x0, unsigned x1,
                                       unsigned &o0, unsigned &o1) {
  unsigned kx = k0 ^ k1 ^ 0x1BD11BDAu;
#define TFR(r) { x0 += x1; x1 = rotl32(x1, (r)); x1 ^= x0; }
  x0 += k0; x1 += k1;
  TFR(13) TFR(15) TFR(26) TFR(6)
  x0 += k1; x1 += kx + 1u;
  TFR(17) TFR(29) TFR(16) TFR(24)
  x0 += kx; x1 += k0 + 2u;
  TFR(13) TFR(15) TFR(26) TFR(6)
  x0 += k0; x1 += k1 + 3u;
  TFR(17) TFR(29) TFR(16) TFR(24)
  x0 += k1; x1 += kx + 4u;
  TFR(13) TFR(15) TFR(26) TFR(6)
  x0 += kx; x1 += k0 + 5u;
#undef TFR
  o0 = x0; o1 = x1;
}

// bits -> u (JAX uniform[tiny,1)) -> t = -ln(u), clamped >= 1e-7
__device__ __forceinline__ float bits_to_t(unsigned bits) {
  float f = __uint_as_float((bits >> 9) | 0x3f800000u) - 1.0f;
  float u = fmaxf(TINYF, f + TINYF);
  return fmaxf(-LN2F * LOG2F(u), 1.0e-7f);
}

// DPP butterfly wave64 sum; result broadcast via readlane(63) -> SGPR
__device__ __forceinline__ float wave_sum64(float x) {
  x += __int_as_float(__builtin_amdgcn_update_dpp(0, __float_as_int(x), 0xB1, 0xF, 0xF, true));   // quad_perm 1,0,3,2
  x += __int_as_float(__builtin_amdgcn_update_dpp(0, __float_as_int(x), 0x4E, 0xF, 0xF, true));   // quad_perm 2,3,0,1
  x += __int_as_float(__builtin_amdgcn_update_dpp(0, __float_as_int(x), 0x141, 0xF, 0xF, true));  // row_half_mirror
  x += __int_as_float(__builtin_amdgcn_update_dpp(0, __float_as_int(x), 0x140, 0xF, 0xF, true));  // row_mirror
  x += __int_as_float(__builtin_amdgcn_update_dpp(0, __float_as_int(x), 0x142, 0xA, 0xF, true));  // row_bcast15 -> rows 1,3
  x += __int_as_float(__builtin_amdgcn_update_dpp(0, __float_as_int(x), 0x143, 0xC, 0xF, true));  // row_bcast31 -> rows 2,3
  return __int_as_float(__builtin_amdgcn_readlane(__float_as_int(x), 63));
}

// keys[s] = fold_in(key(42), s) = threefry2x32((0,42), (0,s))
__global__ void keys_kernel(unsigned* __restrict__ keys) {
  int i = threadIdx.x;                 // 1024 threads, 1 block
  unsigned o0, o1;
  tf2x32(0u, 42u, 0u, (unsigned)i, o0, o1);
  keys[2*i] = o0; keys[2*i+1] = o1;
}

// f (fp32) -> fp16, 131072 elements
__global__ void cast_kernel(const float* __restrict__ f, _Float16* __restrict__ o) {
  int i = blockIdx.x * 256 + threadIdx.x;
  o[i] = (_Float16)f[i];
}

// ---------------- GEMM: P[kc][64][N] partial = A(64xK fp16) @ W(KxN fp32) ---
__global__ __launch_bounds__(256) void gemm_kernel(
    const _Float16* __restrict__ A, const float* __restrict__ W,
    float* __restrict__ P, int K, int N, int KC) {
  __shared__ _Float16 As[64 * 40];
  __shared__ _Float16 Ws[128 * 40];
  const int t = threadIdx.x;
  const int lane = t & 63, w = t >> 6;
  const int c0 = blockIdx.x * 128;
  const int k0beg = blockIdx.y * KC, k0end = k0beg + KC;

  floatx4 acc[4][2];
#pragma unroll
  for (int i = 0; i < 4; ++i)
#pragma unroll
    for (int j = 0; j < 2; ++j) acc[i][j] = (floatx4){0.f, 0.f, 0.f, 0.f};

  const int ar = t >> 2;
  const int ako = (t & 3) * 8;
  const int wn = (t & 31) * 4;
  const int wk = (t >> 5) * 2;

  uint4 av = *(const uint4*)(A + (size_t)ar * K + k0beg + ako);
  float4 wv[2][2];
#pragma unroll
  for (int kk = 0; kk < 2; ++kk) {
    int krow = k0beg + kk * 16 + wk;
    wv[kk][0] = *(const float4*)(W + (size_t)krow * N + c0 + wn);
    wv[kk][1] = *(const float4*)(W + (size_t)(krow + 1) * N + c0 + wn);
  }

  for (int k0 = k0beg; k0 < k0end; k0 += 32) {
    __syncthreads();
    *(uint4*)(&As[ar * 40 + ako]) = av;
#pragma unroll
    for (int kk = 0; kk < 2; ++kk) {
#pragma unroll
      for (int i = 0; i < 4; ++i) {
        const float* p0 = (const float*)&wv[kk][0];
        const float* p1 = (const float*)&wv[kk][1];
        _Float16 h0 = (_Float16)p0[i], h1 = (_Float16)p1[i];
        unsigned u = (unsigned)*(unsigned short*)&h0 |
                     ((unsigned)*(unsigned short*)&h1 << 16);
        *(unsigned*)(&Ws[(wn + i) * 40 + kk * 16 + wk]) = u;
      }
    }
    int kn = k0 + 32;
    if (kn < k0end) {
      av = *(const uint4*)(A + (size_t)ar * K + kn + ako);
#pragma unroll
      for (int kk = 0; kk < 2; ++kk) {
        int krow = kn + kk * 16 + wk;
        wv[kk][0] = *(const float4*)(W + (size_t)krow * N + c0 + wn);
        wv[kk][1] = *(const float4*)(W + (size_t)(krow + 1) * N + c0 + wn);
      }
    }
    __syncthreads();
    const int q = lane >> 4, ml = lane & 15;
    half8 bfrag[2];
#pragma unroll
    for (int nt = 0; nt < 2; ++nt)
      bfrag[nt] = *(const half8*)(&Ws[(w * 32 + nt * 16 + ml) * 40 + q * 8]);
#pragma unroll
    for (int mt = 0; mt < 4; ++mt) {
      half8 afrag = *(const half8*)(&As[(mt * 16 + ml) * 40 + q * 8]);
      acc[mt][0] = __builtin_amdgcn_mfma_f32_16x16x32_f16(afrag, bfrag[0], acc[mt][0], 0, 0, 0);
      acc[mt][1] = __builtin_amdgcn_mfma_f32_16x16x32_f16(afrag, bfrag[1], acc[mt][1], 0, 0, 0);
    }
  }
  const int q = lane >> 4, ml = lane & 15;
  float* Pb = P + (size_t)blockIdx.y * 64 * N;
#pragma unroll
  for (int mt = 0; mt < 4; ++mt)
#pragma unroll
    for (int nt = 0; nt < 2; ++nt)
#pragma unroll
      for (int i = 0; i < 4; ++i) {
        int m = mt * 16 + q * 4 + i;
        int n = c0 + w * 32 + nt * 16 + ml;
        Pb[(size_t)m * N + n] = acc[mt][nt][i];
      }
}

// ---------------- wide partial-sum reduce (for bn3's 16 K-chunks) -----------
__global__ __launch_bounds__(256) void reduce_kernel(
    const float* __restrict__ P, float* __restrict__ X, int nkc, int total) {
  int i = blockIdx.x * 256 + threadIdx.x;
  float s = 0.f;
  for (int kc = 0; kc < nkc; ++kc) s += P[(size_t)kc * total + i];
  X[i] = s;
}

// ---------------- BN epilogue ----------------------------------------------
__global__ __launch_bounds__(256) void bn_kernel(
    const float* __restrict__ P, int nkc, int N,
    const float* __restrict__ g, const float* __restrict__ be,
    _Float16* __restrict__ Hout, float* __restrict__ Fout, int mode) {
  int c = blockIdx.x * 256 + threadIdx.x;
  float x[64];
#pragma unroll
  for (int r = 0; r < 64; ++r) x[r] = 0.f;
  for (int kc = 0; kc < nkc; ++kc) {
    const float* Pb = P + (size_t)kc * 64 * N + c;
#pragma unroll
    for (int r = 0; r < 64; ++r) x[r] += Pb[(size_t)r * N];
  }
  float s = 0.f;
#pragma unroll
  for (int r = 0; r < 64; ++r) s += x[r];
  float mean = s * 0.015625f;
  float v = 0.f;
#pragma unroll
  for (int r = 0; r < 64; ++r) { float d = x[r] - mean; v += d * d; }
  v *= 0.015625f;
  float rs = rsqrtf(v + 1e-5f);
  if (mode == 0) {
    float gg = g[c], bb = be[c];
#pragma unroll
    for (int r = 0; r < 64; ++r) {
      float y = (x[r] - mean) * rs * gg + bb;
      Hout[(size_t)r * N + c] = (_Float16)fmaxf(y, 0.f);
    }
  } else {
#pragma unroll
    for (int r = 0; r < 64; ++r)
      Fout[(size_t)r * N + c] = (x[r] - mean) * rs;
  }
}

// ---------------- noise precompute: t_s=512*(-ln u) fp16 --------------------
// bits(i = r*2048+c) = o0^o1 of tf2x32(keys[s], 0, i).
// layout noise[r][sg][t*8..][j]: us index (t*8+q)*4 + j within group row.
__global__ __launch_bounds__(256) void noise_kernel(
    const unsigned* __restrict__ keys, _Float16* __restrict__ noise) {
  const int bx = blockIdx.x;
  const int r = bx & 63, sg = bx >> 6;
  const int t = threadIdx.x;
  union Pack { unsigned v[16]; unsigned short us[32]; } pa;
#pragma unroll
  for (int j = 0; j < 4; ++j) {
    unsigned kk0 = keys[(sg * 4 + j) * 2];
    unsigned kk1 = keys[(sg * 4 + j) * 2 + 1];
#pragma unroll
    for (int q = 0; q < 8; ++q) {
      unsigned x1 = (unsigned)(r * 2048 + t * 8 + q);
      unsigned o0, o1;
      tf2x32(kk0, kk1, 0u, x1, o0, o1);
      float ts = fmaxf(bits_to_t(COMBINE(o0, o1)) * TSCALE, TS_MIN);
      _Float16 h = (_Float16)ts;
      pa.us[q * 4 + j] = *(unsigned short*)&h;
    }
  }
  size_t base = (((size_t)r * 256 + sg) * 2048 + (size_t)t * 8) * 4;
  uint4* wp = (uint4*)(noise + base);
#pragma unroll
  for (int i = 0; i < 4; ++i) wp[i] = ((uint4*)pa.v)[i];
}

// ---------------- sequential gumbel-softmax scan ----------------------------
// 64 blocks (1 row) x 256 thr, 8 elems/thread.
// MODE 0: p-space recurrence + DPP reduce + 2-group-pipelined lg prep.
// MODE 1: legacy inline-threefry fallback (ws too small for noise buffer).
template <int MODE>
__global__ __launch_bounds__(256) void loop_kernel(
    const float* __restrict__ mask0, const _Float16* __restrict__ noise,
    const unsigned* __restrict__ keys, float* __restrict__ zout) {
  const int row = blockIdx.x;
  const int t = threadIdx.x;
  const int lane = t & 63, w = t >> 6;
  __shared__ __align__(16) float partial[2][4];
  __shared__ unsigned keysLds[2048];

  float p[8], z[8];
  {
    union { float4 v[2]; float f[8]; } mm;
    mm.v[0] = *(const float4*)(mask0 + row * 2048 + t * 8);
    mm.v[1] = *(const float4*)(mask0 + row * 2048 + t * 8 + 4);
#pragma unroll
    for (int q = 0; q < 8; ++q) { p[q] = mm.f[q]; z[q] = 0.f; }
  }

  if (MODE == 0) {
    const _Float16* nbase = noise + (size_t)row * 2097152;  // 256 sg * 8192
    float aC = C2F;                    // step0: e = m0*C2F + lg
    float lgA[8][4], lgB[8][4];
    uint4 nbufA[4], nbufB[4];

    // lg-prep for one step-column j from a group buffer
    auto prep8 = [&](float (&LN)[8][4], const uint4 (&nbC)[4], int j) {
#pragma unroll
      for (int q = 0; q < 8; ++q) {
        int h = q * 4 + j;
        unsigned d = ((const unsigned*)&nbC[h >> 3])[(h >> 1) & 3];
        unsigned short usv = (h & 1) ? (unsigned short)(d >> 16)
                                     : (unsigned short)(d & 0xffffu);
        _Float16 hv;
        __builtin_memcpy(&hv, &usv, 2);
        LN[q][j] = -2.0f * LOG2F((float)hv);
      }
    };

    {  // init: lgA <- group0; nbufA <- group1 data
      uint4 nbI[4];
      const uint4* p0 = (const uint4*)(nbase + (size_t)t * 32);
      nbI[0] = p0[0]; nbI[1] = p0[1]; nbI[2] = p0[2]; nbI[3] = p0[3];
#pragma unroll
      for (int j = 0; j < 4; ++j) prep8(lgA, nbI, j);
      const uint4* p1 = (const uint4*)(nbase + 8192 + (size_t)t * 32);
      nbufA[0] = p1[0]; nbufA[1] = p1[1]; nbufA[2] = p1[2]; nbufA[3] = p1[3];
    }

    // group sg: uses LC; consumes nbC (data sg+1) to build LN (lg of sg+1);
    // issues load of data sg+2 into nbL.
    auto run_group = [&](const float (&LC)[8][4], float (&LN)[8][4],
                         const uint4 (&nbC)[4], uint4 (&nbL)[4], int sg) {
      int gl = (sg + 2 < 256) ? sg + 2 : 255;
      const uint4* pl = (const uint4*)(nbase + (size_t)gl * 8192 + (size_t)t * 32);
      nbL[0] = pl[0]; nbL[1] = pl[1]; nbL[2] = pl[2]; nbL[3] = pl[3];
#pragma unroll
      for (int j = 0; j < 4; ++j) {
        float pn[8];
#pragma unroll
        for (int q = 0; q < 8; ++q)
          pn[q] = EXP2F(fmaf(p[q], aC, LC[q][j]));
        float s = ((pn[0] + pn[1]) + (pn[2] + pn[3])) +
                  ((pn[4] + pn[5]) + (pn[6] + pn[7]));
        s = wave_sum64(s);
        if (lane == 0) partial[j & 1][w] = s;
        __syncthreads();               // slot parity -> 1 barrier/step safe
        float4 ps = *(const float4*)(&partial[j & 1][0]);
        prep8(LN, nbC, j);             // scheduled into ds_read shadow
        float S = (ps.x + ps.y) + (ps.z + ps.w);
        float inv = RCPF(S);
        aC = inv * C2F;
#pragma unroll
        for (int q = 0; q < 8; ++q) {
          z[q] = fmaxf(z[q], pn[q] * inv);
          p[q] = pn[q];
        }
      }
    };

    for (int sgp = 0; sgp < 128; ++sgp) {
      run_group(lgA, lgB, nbufA, nbufB, 2 * sgp);
      run_group(lgB, lgA, nbufB, nbufA, 2 * sgp + 1);
    }
  } else {
    // -------- legacy fallback: inline threefry, old softmax form ----------
    for (int i = t; i < 2048; i += 256) keysLds[i] = keys[i];
    __syncthreads();
    float m[8];
#pragma unroll
    for (int q = 0; q < 8; ++q) m[q] = p[q];
    const unsigned idx0 = (unsigned)(row * 2048 + t * 8);
    for (int sg = 0; sg < 256; ++sg) {
      float rg[8][4];
#pragma unroll
      for (int j = 0; j < 4; ++j) {
        unsigned kk0 = keysLds[(sg * 4 + j) * 2];
        unsigned kk1 = keysLds[(sg * 4 + j) * 2 + 1];
#pragma unroll
        for (int q = 0; q < 8; ++q) {
          unsigned o0, o1;
          tf2x32(kk0, kk1, 0u, idx0 + q, o0, o1);
          float tt = bits_to_t(COMBINE(o0, o1));
          rg[q][j] = RCPF(tt * tt);
        }
      }
#pragma unroll
      for (int j = 0; j < 4; ++j) {
        float pp[8], loc = 0.f;
#pragma unroll
        for (int q = 0; q < 8; ++q) {
          pp[q] = EXP2F(m[q] * C2F) * rg[q][j];
          loc += pp[q];
        }
        loc = wave_sum64(loc);
        if (lane == 0) partial[j & 1][w] = loc;
        __syncthreads();
        float4 ps = *(const float4*)(&partial[j & 1][0]);
        float S = (ps.x + ps.y) + (ps.z + ps.w);
        float inv = RCPF(S);
#pragma unroll
        for (int q = 0; q < 8; ++q) {
          m[q] = pp[q] * inv;
          z[q] = fmaxf(z[q], m[q]);
        }
      }
    }
  }
  union { float4 v[2]; float f[8]; } oo;
#pragma unroll
  for (int q = 0; q < 8; ++q) oo.f[q] = z[q];
  *(float4*)(zout + row * 2048 + t * 8) = oo.v[0];
  *(float4*)(zout + row * 2048 + t * 8 + 4) = oo.v[1];
}

// ---------------- launcher --------------------------------------------------
#define OFF_A0  65536u
#define OFF_H1  327680u
#define OFF_H2  1376256u
#define OFF_M0  2424832u
#define OFF_P   2949120u
#define OFF_XR  19726336u
#define OFF_NOISE 33554432ull
#define NEED_PRE (33554432ull + 268435456ull)

extern "C" void kernel_launch(void* const* d_in, const int* in_sizes, int n_in,
                              void* d_out, int out_size, void* d_ws, size_t ws_size,
                              hipStream_t stream) {
  const float* f   = (const float*)d_in[0];
  const float* W1  = (const float*)d_in[1];
  const float* g1  = (const float*)d_in[3];
  const float* be1 = (const float*)d_in[4];
  const float* W2  = (const float*)d_in[5];
  const float* g2  = (const float*)d_in[7];
  const float* be2 = (const float*)d_in[8];
  const float* W3  = (const float*)d_in[9];

  char* ws = (char*)d_ws;
  unsigned*  keys  = (unsigned*)(ws);
  _Float16*  A0    = (_Float16*)(ws + OFF_A0);
  _Float16*  H1    = (_Float16*)(ws + OFF_H1);
  _Float16*  H2    = (_Float16*)(ws + OFF_H2);
  float*     M0    = (float*)(ws + OFF_M0);
  float*     P     = (float*)(ws + OFF_P);
  float*     Xr    = (float*)(ws + OFF_XR);
  _Float16*  noise = (_Float16*)(ws + OFF_NOISE);
  float*     z     = (float*)d_out;
  bool pre = ws_size >= NEED_PRE;

  keys_kernel<<<1, 1024, 0, stream>>>(keys);
  cast_kernel<<<512, 256, 0, stream>>>(f, A0);
  gemm_kernel<<<dim3(64, 4), 256, 0, stream>>>(A0, W1, P, 2048, 8192, 512);
  bn_kernel<<<32, 256, 0, stream>>>(P, 4, 8192, g1, be1, H1, nullptr, 0);
  gemm_kernel<<<dim3(64, 4), 256, 0, stream>>>(H1, W2, P, 8192, 8192, 2048);
  bn_kernel<<<32, 256, 0, stream>>>(P, 4, 8192, g2, be2, H2, nullptr, 0);
  gemm_kernel<<<dim3(16, 16), 256, 0, stream>>>(H2, W3, P, 8192, 2048, 512);
  reduce_kernel<<<512, 256, 0, stream>>>(P, Xr, 16, 131072);
  bn_kernel<<<8, 256, 0, stream>>>(Xr, 1, 2048, nullptr, nullptr, nullptr, M0, 1);
  if (pre) {
    noise_kernel<<<16384, 256, 0, stream>>>(keys, noise);
    loop_kernel<0><<<64, 256, 0, stream>>>(M0, noise, keys, z);
  } else {
    loop_kernel<1><<<64, 256, 0, stream>>>(M0, nullptr, keys, z);
  }
}